// Round 2
// baseline (388.560 us; speedup 1.0000x reference)
//
#include <hip/hip_runtime.h>

// Problem constants (from reference)
#define NV      163842      // vertices
#define CIN     64
#define NBATCH  2
#define OUTF    64
#define KN      7
#define KDIM    448         // 7*64
#define KSTEPS  14          // 448 / 32
#define VPC     16          // vertices per chunk
#define ROWS    32          // M-rows per chunk (VPC * 2 batches)
#define ASTRIDE 456         // LDS row stride in bf16 units (448 + 8 pad; keeps 16B align)

typedef short  short8 __attribute__((ext_vector_type(8)));
typedef float  f32x4  __attribute__((ext_vector_type(4)));

static __device__ __forceinline__ unsigned int pack_bf16(float a, float b) {
#if __has_builtin(__builtin_amdgcn_cvt_pk_bf16_f32)
    typedef __bf16 bf16x2 __attribute__((ext_vector_type(2)));
    union { bf16x2 v; unsigned int u; } cv;
    cv.v = __builtin_amdgcn_cvt_pk_bf16_f32(a, b);
    return cv.u;
#else
    // round-to-nearest-even truncation to bf16
    unsigned int ua = __float_as_uint(a);
    unsigned int ub = __float_as_uint(b);
    ua = (ua + 0x7FFFu + ((ua >> 16) & 1u)) >> 16;
    ub = (ub + 0x7FFFu + ((ub >> 16) & 1u)) & 0xFFFF0000u;
    return ua | ub;
#endif
}

__global__ __launch_bounds__(256, 2)
void onering_mfma(const float* __restrict__ x,
                  const int* __restrict__ neigh,   // harness passes integer inputs as int32
                  const float* __restrict__ W,
                  const float* __restrict__ bias,
                  float* __restrict__ out,
                  int nchunks)
{
    __shared__ unsigned short A_lds[ROWS * ASTRIDE];   // 32 x 456 bf16 = 29184 B

    const int tid   = threadIdx.x;
    const int lane  = tid & 63;
    const int w     = tid >> 6;      // wave id 0..3
    const int mtile = w & 1;         // which 16-row M-tile of the chunk
    const int ohalf = w >> 1;        // which 32-wide half of O

    const int ncol = lane & 15;      // n (col) within 16-wide tile; also A row within tile
    const int kgrp = lane >> 4;      // 0..3 -> k-subgroup

    // ---- persistent B fragments: W (fp32) -> bf16, register-resident ----
    // B[k][n] frag: lane holds B[kstep*32 + kgrp*8 + j][otile*16 + ncol] = W[o][k]
    short8 bfrag[KSTEPS][2];
#pragma unroll
    for (int s = 0; s < KSTEPS; ++s) {
#pragma unroll
        for (int ot = 0; ot < 2; ++ot) {
            const int o  = ohalf * 32 + ot * 16 + ncol;
            const int kb = s * 32 + kgrp * 8;
            const float4* wp = (const float4*)(W + o * KDIM + kb);
            float4 w0 = wp[0];
            float4 w1 = wp[1];
            union { short8 v; unsigned int u[4]; } pk;
            pk.u[0] = pack_bf16(w0.x, w0.y);
            pk.u[1] = pack_bf16(w0.z, w0.w);
            pk.u[2] = pack_bf16(w1.x, w1.y);
            pk.u[3] = pack_bf16(w1.z, w1.w);
            bfrag[s][ot] = pk.v;
        }
    }
    const float bias0 = bias[ohalf * 32 + ncol];
    const float bias1 = bias[ohalf * 32 + 16 + ncol];

    const int off4  = tid & 31;   // float4 offset within a 512B gathered segment
    const int sbase = tid >> 5;   // 0..7

    for (int ch = blockIdx.x; ch < nchunks; ch += gridDim.x) {
        const int vb = ch * VPC;

        __syncthreads();   // protect A_lds from previous iteration's readers

        // ---- stage: gather 16 vertices x 7 neighbors, fp32 -> bf16 -> LDS ----
        // segment s = lv*7 + k; each segment is x[v]: 128 floats (c,b interleaved)
#pragma unroll
        for (int i = 0; i < 14; ++i) {
            const int s  = sbase + 8 * i;       // 0..111
            const int lv = s / 7;
            const int k  = s - lv * 7;
            const int n  = vb + lv;
            int vi = 0;
            if (n < NV) vi = neigh[n * KN + k];
            const float4 g = ((const float4*)x)[vi * 32 + off4];
            // floats: (c0,b0),(c0,b1),(c0+1,b0),(c0+1,b1) with c0 = 2*off4
            const int base = k * 64 + 2 * off4;           // k-dim position (even)
            const unsigned int lo = pack_bf16(g.x, g.z);  // batch 0: c0, c0+1
            const unsigned int hi = pack_bf16(g.y, g.w);  // batch 1
            ((unsigned int*)A_lds)[((lv * 2)     * ASTRIDE + base) >> 1] = lo;
            ((unsigned int*)A_lds)[((lv * 2 + 1) * ASTRIDE + base) >> 1] = hi;
        }

        __syncthreads();

        // ---- compute: per wave, 16 rows x 32 out-cols ----
        f32x4 acc0 = {0.f, 0.f, 0.f, 0.f};
        f32x4 acc1 = {0.f, 0.f, 0.f, 0.f};
        const int arow = mtile * 16 + ncol;   // A row: lane&15 within tile
#pragma unroll
        for (int s = 0; s < KSTEPS; ++s) {
            const short8 a =
                *(const short8*)&A_lds[arow * ASTRIDE + s * 32 + kgrp * 8];
            acc0 = __builtin_amdgcn_mfma_f32_16x16x32_bf16(a, bfrag[s][0], acc0, 0, 0, 0);
            acc1 = __builtin_amdgcn_mfma_f32_16x16x32_bf16(a, bfrag[s][1], acc1, 0, 0, 0);
        }

        // ---- epilogue: C/D layout col=lane&15, row=(lane>>4)*4+j ----
#pragma unroll
        for (int j = 0; j < 4; ++j) {
            const int r  = kgrp * 4 + j;
            const int m  = mtile * 16 + r;
            const int lv = m >> 1;
            const int bb = m & 1;
            const int n  = vb + lv;
            if (n < NV) {
                const int o0 = ohalf * 32 + ncol;
                out[n * 128 + o0 * 2 + bb]        = acc0[j] + bias0;
                out[n * 128 + (o0 + 16) * 2 + bb] = acc1[j] + bias1;
            }
        }
    }
}

extern "C" void kernel_launch(void* const* d_in, const int* in_sizes, int n_in,
                              void* d_out, int out_size, void* d_ws, size_t ws_size,
                              hipStream_t stream) {
    const float* x     = (const float*)d_in[0];
    const int*   neigh = (const int*)d_in[1];     // int64 in reference -> int32 from harness
    const float* W     = (const float*)d_in[2];
    const float* bias  = (const float*)d_in[3];
    float*       out   = (float*)d_out;

    const int nchunks = (NV + VPC - 1) / VPC;   // 10241
    onering_mfma<<<dim3(1024), dim3(256), 0, stream>>>(x, neigh, W, bias, out, nchunks);
}

// Round 3
// 341.377 us; speedup vs baseline: 1.1382x; 1.1382x over previous
//
#include <hip/hip_runtime.h>

// Problem constants (from reference)
#define NV      163842      // vertices
#define CIN     64
#define NBATCH  2
#define OUTF    64
#define KN      7
#define KDIM    448         // 7*64
#define KSTEPS  14          // 448 / 32
#define VPC     16          // vertices per chunk
#define ROWS    32          // M-rows per chunk (VPC * 2 batches)
#define ASTRIDE 456         // LDS row stride in bf16 units (448 + 8 pad; keeps 16B align)

typedef short  short8 __attribute__((ext_vector_type(8)));
typedef float  f32x4  __attribute__((ext_vector_type(4)));

static __device__ __forceinline__ unsigned int pack_bf16(float a, float b) {
#if __has_builtin(__builtin_amdgcn_cvt_pk_bf16_f32)
    typedef __bf16 bf16x2 __attribute__((ext_vector_type(2)));
    union { bf16x2 v; unsigned int u; } cv;
    cv.v = __builtin_amdgcn_cvt_pk_bf16_f32(a, b);
    return cv.u;
#else
    unsigned int ua = __float_as_uint(a);
    unsigned int ub = __float_as_uint(b);
    ua = (ua + 0x7FFFu + ((ua >> 16) & 1u)) >> 16;
    ub = (ub + 0x7FFFu + ((ub >> 16) & 1u)) & 0xFFFF0000u;
    return ua | ub;
#endif
}

// Each wave owns ONE 16-wide O-tile (bfrag = 56 VGPR, not 112) and computes
// BOTH 16-row M-tiles of the chunk against it. Frees ~56 VGPRs so the
// 14 gather loads in staging can stay in flight, and raises occupancy.
__global__ __launch_bounds__(256, 4)
void onering_mfma(const float* __restrict__ x,
                  const int* __restrict__ neigh,   // int64 in ref -> int32 from harness
                  const float* __restrict__ W,
                  const float* __restrict__ bias,
                  float* __restrict__ out,
                  int nchunks)
{
    __shared__ unsigned short A_lds[ROWS * ASTRIDE];   // 32 x 456 bf16 = 29184 B

    const int tid   = threadIdx.x;
    const int lane  = tid & 63;
    const int w     = tid >> 6;      // wave id 0..3 -> O-tile
    const int ncol  = lane & 15;     // out col within 16-wide tile; also A row within tile
    const int kgrp  = lane >> 4;     // 0..3 -> k-subgroup

    // ---- persistent B fragments: W (fp32) -> bf16, register-resident ----
    // lane holds B[kstep*32 + kgrp*8 + j][w*16 + ncol] = W[o][k]
    short8 bfrag[KSTEPS];
    {
        const int o = w * 16 + ncol;
#pragma unroll
        for (int s = 0; s < KSTEPS; ++s) {
            const int kb = s * 32 + kgrp * 8;
            const float4* wp = (const float4*)(W + o * KDIM + kb);
            float4 w0 = wp[0];
            float4 w1 = wp[1];
            union { short8 v; unsigned int u[4]; } pk;
            pk.u[0] = pack_bf16(w0.x, w0.y);
            pk.u[1] = pack_bf16(w0.z, w0.w);
            pk.u[2] = pack_bf16(w1.x, w1.y);
            pk.u[3] = pack_bf16(w1.z, w1.w);
            bfrag[s] = pk.v;
        }
    }
    const float biasv = bias[w * 16 + ncol];

    const int off4  = tid & 31;   // float4 offset within a 512B gathered segment
    const int sbase = tid >> 5;   // 0..7

    for (int ch = blockIdx.x; ch < nchunks; ch += gridDim.x) {
        const int vb = ch * VPC;

        __syncthreads();   // protect A_lds from previous iteration's readers

        // ---- stage: gather 16 vertices x 7 neighbors, fp32 -> bf16 -> LDS ----
        // segment s = lv*7 + k; each segment is x[v]: 128 floats (c,b interleaved)
#pragma unroll
        for (int i = 0; i < 14; ++i) {
            const int s  = sbase + 8 * i;       // 0..111
            const int lv = s / 7;
            const int k  = s - lv * 7;
            const int n  = vb + lv;
            int vi = 0;
            if (n < NV) vi = neigh[n * KN + k];
            const float4 g = ((const float4*)x)[vi * 32 + off4];
            // floats: (c0,b0),(c0,b1),(c0+1,b0),(c0+1,b1) with c0 = 2*off4
            const int base = k * 64 + 2 * off4;           // k-dim position (even)
            const unsigned int lo = pack_bf16(g.x, g.z);  // batch 0: c0, c0+1
            const unsigned int hi = pack_bf16(g.y, g.w);  // batch 1
            ((unsigned int*)A_lds)[((lv * 2)     * ASTRIDE + base) >> 1] = lo;
            ((unsigned int*)A_lds)[((lv * 2 + 1) * ASTRIDE + base) >> 1] = hi;
        }

        __syncthreads();

        // ---- compute: per wave, 32 rows x 16 out-cols ----
        f32x4 acc0 = {0.f, 0.f, 0.f, 0.f};   // M-tile 0 (rows 0..15)
        f32x4 acc1 = {0.f, 0.f, 0.f, 0.f};   // M-tile 1 (rows 16..31)
#pragma unroll
        for (int s = 0; s < KSTEPS; ++s) {
            const int kb = s * 32 + kgrp * 8;
            const short8 a0 = *(const short8*)&A_lds[ncol * ASTRIDE + kb];
            const short8 a1 = *(const short8*)&A_lds[(16 + ncol) * ASTRIDE + kb];
            acc0 = __builtin_amdgcn_mfma_f32_16x16x32_bf16(a0, bfrag[s], acc0, 0, 0, 0);
            acc1 = __builtin_amdgcn_mfma_f32_16x16x32_bf16(a1, bfrag[s], acc1, 0, 0, 0);
        }

        // ---- epilogue: C/D layout col=lane&15, row=(lane>>4)*4+j ----
        const int o = w * 16 + ncol;
#pragma unroll
        for (int j = 0; j < 4; ++j) {
            const int r = kgrp * 4 + j;
            {   // M-tile 0: m = r
                const int lv = r >> 1, bb = r & 1, n = vb + lv;
                if (n < NV) out[n * 128 + o * 2 + bb] = acc0[j] + biasv;
            }
            {   // M-tile 1: m = 16 + r
                const int m = 16 + r;
                const int lv = m >> 1, bb = m & 1, n = vb + lv;
                if (n < NV) out[n * 128 + o * 2 + bb] = acc1[j] + biasv;
            }
        }
    }
}

extern "C" void kernel_launch(void* const* d_in, const int* in_sizes, int n_in,
                              void* d_out, int out_size, void* d_ws, size_t ws_size,
                              hipStream_t stream) {
    const float* x     = (const float*)d_in[0];
    const int*   neigh = (const int*)d_in[1];
    const float* W     = (const float*)d_in[2];
    const float* bias  = (const float*)d_in[3];
    float*       out   = (float*)d_out;

    const int nchunks = (NV + VPC - 1) / VPC;   // 10241
    // 2560 blocks = 10/CU oversubscription, ~4 chunks each (amortizes bfrag setup)
    onering_mfma<<<dim3(2560), dim3(256), 0, stream>>>(x, neigh, W, bias, out, nchunks);
}

// Round 4
// 248.346 us; speedup vs baseline: 1.5646x; 1.3746x over previous
//
#include <hip/hip_runtime.h>

// Problem constants (from reference)
#define NV      163842      // vertices
#define CIN     64
#define KN      7
#define KDIM    448         // 7*64
#define KSTEPS  14          // 448 / 32
#define VPC     16          // vertices per chunk
#define ROWS    32          // M-rows per chunk (VPC * 2 batches)
#define ASTRIDE 456         // LDS row stride in bf16 units (448 + 8 pad; 912B, 16B-aligned)

typedef short  short8 __attribute__((ext_vector_type(8)));
typedef float  f32x4  __attribute__((ext_vector_type(4)));

static __device__ __forceinline__ unsigned int pack_bf16(float a, float b) {
#if __has_builtin(__builtin_amdgcn_cvt_pk_bf16_f32)
    typedef __bf16 bf16x2 __attribute__((ext_vector_type(2)));
    union { bf16x2 v; unsigned int u; } cv;
    cv.v = __builtin_amdgcn_cvt_pk_bf16_f32(a, b);
    return cv.u;
#else
    unsigned int ua = __float_as_uint(a);
    unsigned int ub = __float_as_uint(b);
    ua = (ua + 0x7FFFu + ((ua >> 16) & 1u)) >> 16;
    ub = (ub + 0x7FFFu + ((ub >> 16) & 1u)) & 0xFFFF0000u;
    return ua | ub;
#endif
}

// ---- pre-pass: x [N][C][B] fp32 -> x_t [B][N][C] bf16 (de-interleave + cast) ----
// One float4 per thread = (c0,b0),(c0,b1),(c0+1,b0),(c0+1,b1). Both loads and
// the two u32 stores are fully coalesced.
__global__ __launch_bounds__(256)
void xcast(const float* __restrict__ x, unsigned int* __restrict__ xt, int nf4)
{
    const int f = blockIdx.x * 256 + threadIdx.x;   // float4 index over x
    if (f >= nf4) return;                           // nf4 = NV*32
    const float4 g = ((const float4*)x)[f];
    const int v = f >> 5;
    const int r = f & 31;                           // u32 slot; c0 = 2r
    xt[v * 32 + r]           = pack_bf16(g.x, g.z); // batch 0: c0, c0+1
    xt[NV * 32 + v * 32 + r] = pack_bf16(g.y, g.w); // batch 1
}

// ---- main: gather bf16 -> LDS (pure 16B copies) -> MFMA -> LDS -> coalesced out ----
__global__ __launch_bounds__(256, 4)
void onering_mfma_bf16(const unsigned short* __restrict__ xt,
                       const int* __restrict__ neigh,
                       const float* __restrict__ W,
                       const float* __restrict__ bias,
                       float* __restrict__ out,
                       int nchunks)
{
    __shared__ unsigned short A_lds[ROWS * ASTRIDE];   // 29184 B
    __shared__ float          C_lds[VPC * 128];        // 8192 B  (out-layout staging)

    const int tid  = threadIdx.x;
    const int lane = tid & 63;
    const int w    = tid >> 6;       // wave id 0..3 -> 16-wide O-tile
    const int ncol = lane & 15;
    const int kgrp = lane >> 4;

    // ---- persistent B fragments: W (fp32) -> bf16, register-resident (56 VGPR) ----
    short8 bfrag[KSTEPS];
    {
        const int o = w * 16 + ncol;
#pragma unroll
        for (int s = 0; s < KSTEPS; ++s) {
            const int kb = s * 32 + kgrp * 8;
            const float4* wp = (const float4*)(W + o * KDIM + kb);
            float4 w0 = wp[0];
            float4 w1 = wp[1];
            union { short8 v; unsigned int u[4]; } pk;
            pk.u[0] = pack_bf16(w0.x, w0.y);
            pk.u[1] = pack_bf16(w0.z, w0.w);
            pk.u[2] = pack_bf16(w1.x, w1.y);
            pk.u[3] = pack_bf16(w1.z, w1.w);
            bfrag[s] = pk.v;
        }
    }
    const float biasv = bias[w * 16 + ncol];

    // ---- staging plan: 224 segments (row 0..31, k 0..6), 8 lanes x 16B each ----
    // seg_i = (tid>>3) + 32*i, i = 0..6. All loop-invariant parts precomputed.
    const int l8 = tid & 7;
    int nidx[7];      // lv*7 + k      (neigh offset within chunk)
    int lbyte[7];     // byte addr in A_lds
    int soff[7];      // short offset within xt: bb*NV*64 + l8*8
#pragma unroll
    for (int i = 0; i < 7; ++i) {
        const int seg = (tid >> 3) + 32 * i;
        const int row = seg / 7;          // magic-mul
        const int k   = seg - row * 7;
        const int lv  = row >> 1, bb = row & 1;
        nidx[i]  = lv * KN + k;
        lbyte[i] = row * (ASTRIDE * 2) + k * 128 + l8 * 16;
        soff[i]  = bb * (NV * 64) + l8 * 8;
    }

    for (int ch = blockIdx.x; ch < nchunks; ch += gridDim.x) {
        const int vb  = ch * VPC;
        const int vb7 = vb * KN;

        __syncthreads();   // previous iteration's C_lds readers done

        // ---- gather stage: 7 independent 16B load -> ds_write_b128, no VALU ----
#pragma unroll
        for (int i = 0; i < 7; ++i) {
            const int gi = vb7 + nidx[i];
            const int vi = (gi < NV * KN) ? neigh[gi] : 0;
            const short8 v = *(const short8*)(xt + soff[i] + vi * 64);
            *(short8*)((char*)A_lds + lbyte[i]) = v;
        }
        __syncthreads();

        // ---- compute: per wave, 32 rows x 16 out-cols ----
        f32x4 acc0 = {0.f, 0.f, 0.f, 0.f};
        f32x4 acc1 = {0.f, 0.f, 0.f, 0.f};
#pragma unroll
        for (int s = 0; s < KSTEPS; ++s) {
            const int kb = s * 32 + kgrp * 8;
            const short8 a0 = *(const short8*)&A_lds[ncol * ASTRIDE + kb];
            const short8 a1 = *(const short8*)&A_lds[(16 + ncol) * ASTRIDE + kb];
            acc0 = __builtin_amdgcn_mfma_f32_16x16x32_bf16(a0, bfrag[s], acc0, 0, 0, 0);
            acc1 = __builtin_amdgcn_mfma_f32_16x16x32_bf16(a1, bfrag[s], acc1, 0, 0, 0);
        }

        // ---- epilogue: C -> LDS in out-layout [lv][o][b] fp32 ----
        const int o2 = (w * 16 + ncol) * 2;
#pragma unroll
        for (int j = 0; j < 4; ++j) {
            const int r  = kgrp * 4 + j;        // M-tile 0: rows 0..15
            C_lds[(r >> 1) * 128 + o2 + (r & 1)] = acc0[j] + biasv;
            const int r2 = 16 + r;              // M-tile 1: rows 16..31
            C_lds[(r2 >> 1) * 128 + o2 + (r2 & 1)] = acc1[j] + biasv;
        }
        __syncthreads();

        // ---- coalesced store: 2 x float4 per thread (8 KB per chunk) ----
        float4* dst = (float4*)(out + vb * 128);
#pragma unroll
        for (int it = 0; it < 2; ++it) {
            const int fidx = tid + 256 * it;
            if (vb + (fidx >> 5) < NV)
                dst[fidx] = ((const float4*)C_lds)[fidx];
        }
    }
}

// ---- fallback (ws too small): round-3 fp32-gather kernel ----
__global__ __launch_bounds__(256, 4)
void onering_mfma_f32(const float* __restrict__ x,
                      const int* __restrict__ neigh,
                      const float* __restrict__ W,
                      const float* __restrict__ bias,
                      float* __restrict__ out,
                      int nchunks)
{
    __shared__ unsigned short A_lds[ROWS * ASTRIDE];
    const int tid  = threadIdx.x;
    const int lane = tid & 63;
    const int w    = tid >> 6;
    const int ncol = lane & 15;
    const int kgrp = lane >> 4;

    short8 bfrag[KSTEPS];
    {
        const int o = w * 16 + ncol;
#pragma unroll
        for (int s = 0; s < KSTEPS; ++s) {
            const int kb = s * 32 + kgrp * 8;
            const float4* wp = (const float4*)(W + o * KDIM + kb);
            float4 w0 = wp[0];
            float4 w1 = wp[1];
            union { short8 v; unsigned int u[4]; } pk;
            pk.u[0] = pack_bf16(w0.x, w0.y);
            pk.u[1] = pack_bf16(w0.z, w0.w);
            pk.u[2] = pack_bf16(w1.x, w1.y);
            pk.u[3] = pack_bf16(w1.z, w1.w);
            bfrag[s] = pk.v;
        }
    }
    const float biasv = bias[w * 16 + ncol];
    const int off4  = tid & 31;
    const int sbase = tid >> 5;

    for (int ch = blockIdx.x; ch < nchunks; ch += gridDim.x) {
        const int vb = ch * VPC;
        __syncthreads();
#pragma unroll
        for (int i = 0; i < 14; ++i) {
            const int s  = sbase + 8 * i;
            const int lv = s / 7;
            const int k  = s - lv * 7;
            const int n  = vb + lv;
            int vi = 0;
            if (n < NV) vi = neigh[n * KN + k];
            const float4 g = ((const float4*)x)[vi * 32 + off4];
            const int base = k * 64 + 2 * off4;
            ((unsigned int*)A_lds)[((lv * 2)     * ASTRIDE + base) >> 1] = pack_bf16(g.x, g.z);
            ((unsigned int*)A_lds)[((lv * 2 + 1) * ASTRIDE + base) >> 1] = pack_bf16(g.y, g.w);
        }
        __syncthreads();
        f32x4 acc0 = {0.f, 0.f, 0.f, 0.f};
        f32x4 acc1 = {0.f, 0.f, 0.f, 0.f};
#pragma unroll
        for (int s = 0; s < KSTEPS; ++s) {
            const int kb = s * 32 + kgrp * 8;
            const short8 a0 = *(const short8*)&A_lds[ncol * ASTRIDE + kb];
            const short8 a1 = *(const short8*)&A_lds[(16 + ncol) * ASTRIDE + kb];
            acc0 = __builtin_amdgcn_mfma_f32_16x16x32_bf16(a0, bfrag[s], acc0, 0, 0, 0);
            acc1 = __builtin_amdgcn_mfma_f32_16x16x32_bf16(a1, bfrag[s], acc1, 0, 0, 0);
        }
        const int o = w * 16 + ncol;
#pragma unroll
        for (int j = 0; j < 4; ++j) {
            const int r = kgrp * 4 + j;
            {
                const int lv = r >> 1, bb = r & 1, n = vb + lv;
                if (n < NV) out[n * 128 + o * 2 + bb] = acc0[j] + biasv;
            }
            {
                const int m = 16 + r;
                const int lv = m >> 1, bb = m & 1, n = vb + lv;
                if (n < NV) out[n * 128 + o * 2 + bb] = acc1[j] + biasv;
            }
        }
    }
}

extern "C" void kernel_launch(void* const* d_in, const int* in_sizes, int n_in,
                              void* d_out, int out_size, void* d_ws, size_t ws_size,
                              hipStream_t stream) {
    const float* x     = (const float*)d_in[0];
    const int*   neigh = (const int*)d_in[1];   // int64 in ref -> int32 from harness
    const float* W     = (const float*)d_in[2];
    const float* bias  = (const float*)d_in[3];
    float*       out   = (float*)d_out;

    const int nchunks = (NV + VPC - 1) / VPC;   // 10241
    const size_t need = (size_t)2 * NV * 64 * sizeof(unsigned short);  // 41.9 MB

    if (ws_size >= need) {
        unsigned short* xt = (unsigned short*)d_ws;
        const int nf4 = NV * 32;                        // 5,242,944 float4s
        xcast<<<dim3((nf4 + 255) / 256), dim3(256), 0, stream>>>(x, (unsigned int*)xt, nf4);
        onering_mfma_bf16<<<dim3(2560), dim3(256), 0, stream>>>(xt, neigh, W, bias, out, nchunks);
    } else {
        onering_mfma_f32<<<dim3(2560), dim3(256), 0, stream>>>(x, neigh, W, bias, out, nchunks);
    }
}

// Round 5
// 214.830 us; speedup vs baseline: 1.8087x; 1.1560x over previous
//
#include <hip/hip_runtime.h>

// Problem constants (from reference)
#define NV      163842      // vertices
#define CIN     64
#define KN      7
#define NKMAX   (NV * KN)   // 1,146,894 valid neigh entries
#define KDIM    448         // 7*64
#define KSTEPS  14          // 448 / 32
#define VPC     16          // vertices per chunk
#define ROWS    32          // M-rows per chunk (VPC * 2 batches)
#define ASTRIDE 456         // LDS row stride in bf16 units (448 + 8 pad; 912B, 16B-aligned)

typedef short  short8 __attribute__((ext_vector_type(8)));
typedef float  f32x4  __attribute__((ext_vector_type(4)));

static __device__ __forceinline__ unsigned int pack_bf16(float a, float b) {
#if __has_builtin(__builtin_amdgcn_cvt_pk_bf16_f32)
    typedef __bf16 bf16x2 __attribute__((ext_vector_type(2)));
    union { bf16x2 v; unsigned int u; } cv;
    cv.v = __builtin_amdgcn_cvt_pk_bf16_f32(a, b);
    return cv.u;
#else
    unsigned int ua = __float_as_uint(a);
    unsigned int ub = __float_as_uint(b);
    ua = (ua + 0x7FFFu + ((ua >> 16) & 1u)) >> 16;
    ub = (ub + 0x7FFFu + ((ub >> 16) & 1u)) & 0xFFFF0000u;
    return ua | ub;
#endif
}

// LDS-only barrier: drains lgkmcnt but leaves the vmcnt (global prefetch) queue
// alive across s_barrier. __syncthreads() would emit s_waitcnt vmcnt(0) and
// destroy the cross-chunk pipeline.
static __device__ __forceinline__ void bar_lgkm() {
    asm volatile("s_waitcnt lgkmcnt(0)\n\ts_barrier" ::: "memory");
}

// ---- pre-pass: x [N][C][B] fp32 -> x_t [B][N][C] bf16 (de-interleave + cast) ----
__global__ __launch_bounds__(256)
void xcast(const float* __restrict__ x, unsigned int* __restrict__ xt, int nf4)
{
    const int f = blockIdx.x * 256 + threadIdx.x;   // float4 index over x
    if (f >= nf4) return;                           // nf4 = NV*32
    const float4 g = ((const float4*)x)[f];
    const int v = f >> 5;
    const int r = f & 31;                           // u32 slot; c0 = 2r
    xt[v * 32 + r]           = pack_bf16(g.x, g.z); // batch 0: c0, c0+1
    xt[NV * 32 + v * 32 + r] = pack_bf16(g.y, g.w); // batch 1
}

// ---- main: 3-stage pipelined gather -> LDS -> MFMA -> coalesced out ----
// Stage rotation per iteration (chunk c):   [all in flight simultaneously]
//   ds_write  data(c)      -> A_lds
//   issue     data(c+G)    (addresses from idx regs loaded last iter)
//   issue     idx(c+2G)
__global__ __launch_bounds__(256, 3)
void onering_mfma_bf16(const unsigned short* __restrict__ xt,
                       const int* __restrict__ neigh,
                       const float* __restrict__ W,
                       const float* __restrict__ bias,
                       float* __restrict__ out,
                       int nchunks)
{
    __shared__ unsigned short A_lds[ROWS * ASTRIDE];   // 29184 B
    __shared__ float          C_lds[VPC * 128];        // 8192 B

    const int tid  = threadIdx.x;
    const int lane = tid & 63;
    const int w    = tid >> 6;       // wave id 0..3 -> 16-wide O-tile
    const int ncol = lane & 15;
    const int kgrp = lane >> 4;
    const int G    = gridDim.x;

    // ---- persistent B fragments: W (fp32) -> bf16, register-resident (56 VGPR) ----
    short8 bfrag[KSTEPS];
    {
        const int o = w * 16 + ncol;
#pragma unroll
        for (int s = 0; s < KSTEPS; ++s) {
            const int kb = s * 32 + kgrp * 8;
            const float4* wp = (const float4*)(W + o * KDIM + kb);
            float4 w0 = wp[0];
            float4 w1 = wp[1];
            union { short8 v; unsigned int u[4]; } pk;
            pk.u[0] = pack_bf16(w0.x, w0.y);
            pk.u[1] = pack_bf16(w0.z, w0.w);
            pk.u[2] = pack_bf16(w1.x, w1.y);
            pk.u[3] = pack_bf16(w1.z, w1.w);
            bfrag[s] = pk.v;
        }
    }
    const float biasv = bias[w * 16 + ncol];

    // ---- staging plan: 224 segments (row 0..31, k 0..6), 8 lanes x 16B each ----
    const int l8 = tid & 7;
    int nidx[7];      // lv*7 + k      (neigh offset within chunk)
    int lbyte[7];     // byte addr in A_lds
    int soff[7];      // short offset within xt: bb*NV*64 + l8*8
#pragma unroll
    for (int i = 0; i < 7; ++i) {
        const int seg = (tid >> 3) + 32 * i;
        const int row = seg / 7;
        const int k   = seg - row * 7;
        const int lv  = row >> 1, bb = row & 1;
        nidx[i]  = lv * KN + k;
        lbyte[i] = row * (ASTRIDE * 2) + k * 128 + l8 * 16;
        soff[i]  = bb * (NV * 64) + l8 * 8;
    }

    const int ch0 = blockIdx.x;
    int    I[7];      // neigh indices for chunk c+G
    short8 R[7];      // gathered data for chunk c

    // ---- prologue: fill the pipeline for ch0 ----
#pragma unroll
    for (int i = 0; i < 7; ++i) {
        int gi = ch0 * (VPC * KN) + nidx[i];
        I[i] = neigh[gi < NKMAX ? gi : 0];
    }
#pragma unroll
    for (int i = 0; i < 7; ++i)
        R[i] = *(const short8*)(xt + soff[i] + I[i] * 64);
#pragma unroll
    for (int i = 0; i < 7; ++i) {
        int gi = (ch0 + G) * (VPC * KN) + nidx[i];
        I[i] = neigh[gi < NKMAX ? gi : 0];
    }

    for (int ch = ch0; ch < nchunks; ch += G) {
        const int vb = ch * VPC;

        bar_lgkm();   // prev iter's A_lds reads + C_lds reads done

        // ---- commit current chunk's data to LDS; refill pipeline ----
#pragma unroll
        for (int i = 0; i < 7; ++i)
            *(short8*)((char*)A_lds + lbyte[i]) = R[i];
#pragma unroll
        for (int i = 0; i < 7; ++i)                       // data for ch+G
            R[i] = *(const short8*)(xt + soff[i] + I[i] * 64);
#pragma unroll
        for (int i = 0; i < 7; ++i) {                     // idx for ch+2G
            int gi = (ch + 2 * G) * (VPC * KN) + nidx[i];
            I[i] = neigh[gi < NKMAX ? gi : 0];
        }

        bar_lgkm();   // A_lds populated

        // ---- compute: per wave, 32 rows x 16 out-cols ----
        f32x4 acc0 = {0.f, 0.f, 0.f, 0.f};
        f32x4 acc1 = {0.f, 0.f, 0.f, 0.f};
#pragma unroll
        for (int s = 0; s < KSTEPS; ++s) {
            const int kb = s * 32 + kgrp * 8;
            const short8 a0 = *(const short8*)&A_lds[ncol * ASTRIDE + kb];
            const short8 a1 = *(const short8*)&A_lds[(16 + ncol) * ASTRIDE + kb];
            acc0 = __builtin_amdgcn_mfma_f32_16x16x32_bf16(a0, bfrag[s], acc0, 0, 0, 0);
            acc1 = __builtin_amdgcn_mfma_f32_16x16x32_bf16(a1, bfrag[s], acc1, 0, 0, 0);
        }

        // ---- epilogue: C -> LDS in out-layout [lv][o][b] fp32 ----
        const int o2 = (w * 16 + ncol) * 2;
#pragma unroll
        for (int j = 0; j < 4; ++j) {
            const int r  = kgrp * 4 + j;
            C_lds[(r >> 1) * 128 + o2 + (r & 1)] = acc0[j] + biasv;
            const int r2 = 16 + r;
            C_lds[(r2 >> 1) * 128 + o2 + (r2 & 1)] = acc1[j] + biasv;
        }

        bar_lgkm();   // C_lds populated

        // ---- coalesced store: 2 x float4 per thread ----
        float4* dst = (float4*)(out + vb * 128);
#pragma unroll
        for (int it = 0; it < 2; ++it) {
            const int fidx = tid + 256 * it;
            if (vb + (fidx >> 5) < NV)
                dst[fidx] = ((const float4*)C_lds)[fidx];
        }
    }
}

// ---- fallback (ws too small): fp32-gather kernel ----
__global__ __launch_bounds__(256, 4)
void onering_mfma_f32(const float* __restrict__ x,
                      const int* __restrict__ neigh,
                      const float* __restrict__ W,
                      const float* __restrict__ bias,
                      float* __restrict__ out,
                      int nchunks)
{
    __shared__ unsigned short A_lds[ROWS * ASTRIDE];
    const int tid  = threadIdx.x;
    const int lane = tid & 63;
    const int w    = tid >> 6;
    const int ncol = lane & 15;
    const int kgrp = lane >> 4;

    short8 bfrag[KSTEPS];
    {
        const int o = w * 16 + ncol;
#pragma unroll
        for (int s = 0; s < KSTEPS; ++s) {
            const int kb = s * 32 + kgrp * 8;
            const float4* wp = (const float4*)(W + o * KDIM + kb);
            float4 w0 = wp[0];
            float4 w1 = wp[1];
            union { short8 v; unsigned int u[4]; } pk;
            pk.u[0] = pack_bf16(w0.x, w0.y);
            pk.u[1] = pack_bf16(w0.z, w0.w);
            pk.u[2] = pack_bf16(w1.x, w1.y);
            pk.u[3] = pack_bf16(w1.z, w1.w);
            bfrag[s] = pk.v;
        }
    }
    const float biasv = bias[w * 16 + ncol];
    const int off4  = tid & 31;
    const int sbase = tid >> 5;

    for (int ch = blockIdx.x; ch < nchunks; ch += gridDim.x) {
        const int vb = ch * VPC;
        __syncthreads();
#pragma unroll
        for (int i = 0; i < 14; ++i) {
            const int s  = sbase + 8 * i;
            const int lv = s / 7;
            const int k  = s - lv * 7;
            const int n  = vb + lv;
            int vi = 0;
            if (n < NV) vi = neigh[n * KN + k];
            const float4 g = ((const float4*)x)[vi * 32 + off4];
            const int base = k * 64 + 2 * off4;
            ((unsigned int*)A_lds)[((lv * 2)     * ASTRIDE + base) >> 1] = pack_bf16(g.x, g.z);
            ((unsigned int*)A_lds)[((lv * 2 + 1) * ASTRIDE + base) >> 1] = pack_bf16(g.y, g.w);
        }
        __syncthreads();
        f32x4 acc0 = {0.f, 0.f, 0.f, 0.f};
        f32x4 acc1 = {0.f, 0.f, 0.f, 0.f};
#pragma unroll
        for (int s = 0; s < KSTEPS; ++s) {
            const int kb = s * 32 + kgrp * 8;
            const short8 a0 = *(const short8*)&A_lds[ncol * ASTRIDE + kb];
            const short8 a1 = *(const short8*)&A_lds[(16 + ncol) * ASTRIDE + kb];
            acc0 = __builtin_amdgcn_mfma_f32_16x16x32_bf16(a0, bfrag[s], acc0, 0, 0, 0);
            acc1 = __builtin_amdgcn_mfma_f32_16x16x32_bf16(a1, bfrag[s], acc1, 0, 0, 0);
        }
        const int o = w * 16 + ncol;
#pragma unroll
        for (int j = 0; j < 4; ++j) {
            const int r = kgrp * 4 + j;
            {
                const int lv = r >> 1, bb = r & 1, n = vb + lv;
                if (n < NV) out[n * 128 + o * 2 + bb] = acc0[j] + biasv;
            }
            {
                const int m = 16 + r;
                const int lv = m >> 1, bb = m & 1, n = vb + lv;
                if (n < NV) out[n * 128 + o * 2 + bb] = acc1[j] + biasv;
            }
        }
    }
}

extern "C" void kernel_launch(void* const* d_in, const int* in_sizes, int n_in,
                              void* d_out, int out_size, void* d_ws, size_t ws_size,
                              hipStream_t stream) {
    const float* x     = (const float*)d_in[0];
    const int*   neigh = (const int*)d_in[1];   // int64 in ref -> int32 from harness
    const float* W     = (const float*)d_in[2];
    const float* bias  = (const float*)d_in[3];
    float*       out   = (float*)d_out;

    const int nchunks = (NV + VPC - 1) / VPC;   // 10241
    const size_t need = (size_t)2 * NV * 64 * sizeof(unsigned short);  // 41.9 MB

    if (ws_size >= need) {
        unsigned short* xt = (unsigned short*)d_ws;
        const int nf4 = NV * 32;
        xcast<<<dim3((nf4 + 255) / 256), dim3(256), 0, stream>>>(x, (unsigned int*)xt, nf4);
        onering_mfma_bf16<<<dim3(2560), dim3(256), 0, stream>>>(xt, neigh, W, bias, out, nchunks);
    } else {
        onering_mfma_f32<<<dim3(2560), dim3(256), 0, stream>>>(x, neigh, W, bias, out, nchunks);
    }
}

// Round 7
// 212.646 us; speedup vs baseline: 1.8273x; 1.0103x over previous
//
#include <hip/hip_runtime.h>

// Problem constants (from reference)
#define NV      163842      // vertices
#define CIN     64
#define KN      7
#define NKMAX   (NV * KN)   // 1,146,894 valid neigh entries
#define KDIM    448         // 7*64
#define KSTEPS  14          // 448 / 32
#define VPC     16          // vertices per chunk
#define ROWS    32          // M-rows per chunk (VPC * 2 batches)
#define ASTRIDE 456         // LDS row stride in bf16 units (448 + 8 pad; 912B, 16B-aligned)

typedef short  short8 __attribute__((ext_vector_type(8)));
typedef float  f32x4  __attribute__((ext_vector_type(4)));

static __device__ __forceinline__ unsigned int pack_bf16(float a, float b) {
#if __has_builtin(__builtin_amdgcn_cvt_pk_bf16_f32)
    typedef __bf16 bf16x2 __attribute__((ext_vector_type(2)));
    union { bf16x2 v; unsigned int u; } cv;
    cv.v = __builtin_amdgcn_cvt_pk_bf16_f32(a, b);
    return cv.u;
#else
    unsigned int ua = __float_as_uint(a);
    unsigned int ub = __float_as_uint(b);
    ua = (ua + 0x7FFFu + ((ua >> 16) & 1u)) >> 16;
    ub = (ub + 0x7FFFu + ((ub >> 16) & 1u)) & 0xFFFF0000u;
    return ua | ub;
#endif
}

// LDS-only barrier: drains lgkmcnt but leaves the vmcnt (global prefetch) queue
// alive across s_barrier. __syncthreads() would emit s_waitcnt vmcnt(0) and
// destroy the cross-chunk pipeline.
static __device__ __forceinline__ void bar_lgkm() {
    asm volatile("s_waitcnt lgkmcnt(0)\n\ts_barrier" ::: "memory");
}

// ---- pre-pass: x [N][C][B] fp32 -> x_t [B][N][C] bf16 (de-interleave + cast) ----
// x is read-once: nontemporal loads keep it from evicting the L3 working set.
// xt stores stay CACHED — the main kernel wants xt resident in L3.
__global__ __launch_bounds__(256)
void xcast(const float* __restrict__ x, unsigned int* __restrict__ xt, int nf4)
{
    const int f = blockIdx.x * 256 + threadIdx.x;   // float4 index over x
    if (f >= nf4) return;                           // nf4 = NV*32
    const f32x4 g = __builtin_nontemporal_load(&((const f32x4*)x)[f]);
    const int v = f >> 5;
    const int r = f & 31;                           // u32 slot; c0 = 2r
    xt[v * 32 + r]           = pack_bf16(g[0], g[2]); // batch 0: c0, c0+1
    xt[NV * 32 + v * 32 + r] = pack_bf16(g[1], g[3]); // batch 1
}

// ---- main: 3-stage pipelined gather -> LDS -> MFMA -> coalesced nt out ----
__global__ __launch_bounds__(256, 3)
void onering_mfma_bf16(const unsigned short* __restrict__ xt,
                       const int* __restrict__ neigh,
                       const float* __restrict__ W,
                       const float* __restrict__ bias,
                       float* __restrict__ out,
                       int nchunks)
{
    __shared__ unsigned short A_lds[ROWS * ASTRIDE];   // 29184 B
    __shared__ float          C_lds[VPC * 128];        // 8192 B

    const int tid  = threadIdx.x;
    const int lane = tid & 63;
    const int w    = tid >> 6;       // wave id 0..3 -> 16-wide O-tile
    const int ncol = lane & 15;
    const int kgrp = lane >> 4;
    const int G    = gridDim.x;

    // ---- persistent B fragments: W (fp32) -> bf16, register-resident (56 VGPR) ----
    short8 bfrag[KSTEPS];
    {
        const int o = w * 16 + ncol;
#pragma unroll
        for (int s = 0; s < KSTEPS; ++s) {
            const int kb = s * 32 + kgrp * 8;
            const float4* wp = (const float4*)(W + o * KDIM + kb);
            float4 w0 = wp[0];
            float4 w1 = wp[1];
            union { short8 v; unsigned int u[4]; } pk;
            pk.u[0] = pack_bf16(w0.x, w0.y);
            pk.u[1] = pack_bf16(w0.z, w0.w);
            pk.u[2] = pack_bf16(w1.x, w1.y);
            pk.u[3] = pack_bf16(w1.z, w1.w);
            bfrag[s] = pk.v;
        }
    }
    const float biasv = bias[w * 16 + ncol];

    // ---- staging plan: 224 segments (row 0..31, k 0..6), 8 lanes x 16B each ----
    const int l8 = tid & 7;
    int nidx[7];      // lv*7 + k      (neigh offset within chunk)
    int lbyte[7];     // byte addr in A_lds
    int soff[7];      // short offset within xt: bb*NV*64 + l8*8
#pragma unroll
    for (int i = 0; i < 7; ++i) {
        const int seg = (tid >> 3) + 32 * i;
        const int row = seg / 7;
        const int k   = seg - row * 7;
        const int lv  = row >> 1, bb = row & 1;
        nidx[i]  = lv * KN + k;
        lbyte[i] = row * (ASTRIDE * 2) + k * 128 + l8 * 16;
        soff[i]  = bb * (NV * 64) + l8 * 8;
    }

    const int ch0 = blockIdx.x;
    int    I[7];      // neigh indices for next chunk's gather
    short8 R[7];      // gathered data for current chunk

    // ---- prologue: fill the pipeline for ch0 ----
#pragma unroll
    for (int i = 0; i < 7; ++i) {
        int gi = ch0 * (VPC * KN) + nidx[i];
        I[i] = __builtin_nontemporal_load(&neigh[gi < NKMAX ? gi : 0]);
    }
#pragma unroll
    for (int i = 0; i < 7; ++i)
        R[i] = *(const short8*)(xt + soff[i] + I[i] * 64);
#pragma unroll
    for (int i = 0; i < 7; ++i) {
        int gi = (ch0 + G) * (VPC * KN) + nidx[i];
        I[i] = __builtin_nontemporal_load(&neigh[gi < NKMAX ? gi : 0]);
    }

    for (int ch = ch0; ch < nchunks; ch += G) {
        const int vb = ch * VPC;

        bar_lgkm();   // prev iter's A_lds reads + C_lds reads done

        // ---- commit current chunk's data to LDS; refill pipeline ----
#pragma unroll
        for (int i = 0; i < 7; ++i)
            *(short8*)((char*)A_lds + lbyte[i]) = R[i];
#pragma unroll
        for (int i = 0; i < 7; ++i)                       // data for ch+G
            R[i] = *(const short8*)(xt + soff[i] + I[i] * 64);
#pragma unroll
        for (int i = 0; i < 7; ++i) {                     // idx for ch+2G
            int gi = (ch + 2 * G) * (VPC * KN) + nidx[i];
            I[i] = __builtin_nontemporal_load(&neigh[gi < NKMAX ? gi : 0]);
        }

        bar_lgkm();   // A_lds populated

        // ---- compute: per wave, 32 rows x 16 out-cols ----
        f32x4 acc0 = {0.f, 0.f, 0.f, 0.f};
        f32x4 acc1 = {0.f, 0.f, 0.f, 0.f};
#pragma unroll
        for (int s = 0; s < KSTEPS; ++s) {
            const int kb = s * 32 + kgrp * 8;
            const short8 a0 = *(const short8*)&A_lds[ncol * ASTRIDE + kb];
            const short8 a1 = *(const short8*)&A_lds[(16 + ncol) * ASTRIDE + kb];
            acc0 = __builtin_amdgcn_mfma_f32_16x16x32_bf16(a0, bfrag[s], acc0, 0, 0, 0);
            acc1 = __builtin_amdgcn_mfma_f32_16x16x32_bf16(a1, bfrag[s], acc1, 0, 0, 0);
        }

        // ---- epilogue: C -> LDS in out-layout [lv][o][b] fp32 ----
        const int o2 = (w * 16 + ncol) * 2;
#pragma unroll
        for (int j = 0; j < 4; ++j) {
            const int r  = kgrp * 4 + j;
            C_lds[(r >> 1) * 128 + o2 + (r & 1)] = acc0[j] + biasv;
            const int r2 = 16 + r;
            C_lds[(r2 >> 1) * 128 + o2 + (r2 & 1)] = acc1[j] + biasv;
        }

        bar_lgkm();   // C_lds populated

        // ---- coalesced NON-TEMPORAL store: don't evict xt from L3 ----
        f32x4* dst = (f32x4*)(out + vb * 128);
#pragma unroll
        for (int it = 0; it < 2; ++it) {
            const int fidx = tid + 256 * it;
            if (vb + (fidx >> 5) < NV)
                __builtin_nontemporal_store(((const f32x4*)C_lds)[fidx], &dst[fidx]);
        }
    }
}

// ---- fallback (ws too small): fp32-gather kernel ----
__global__ __launch_bounds__(256, 4)
void onering_mfma_f32(const float* __restrict__ x,
                      const int* __restrict__ neigh,
                      const float* __restrict__ W,
                      const float* __restrict__ bias,
                      float* __restrict__ out,
                      int nchunks)
{
    __shared__ unsigned short A_lds[ROWS * ASTRIDE];
    const int tid  = threadIdx.x;
    const int lane = tid & 63;
    const int w    = tid >> 6;
    const int ncol = lane & 15;
    const int kgrp = lane >> 4;

    short8 bfrag[KSTEPS];
    {
        const int o = w * 16 + ncol;
#pragma unroll
        for (int s = 0; s < KSTEPS; ++s) {
            const int kb = s * 32 + kgrp * 8;
            const float4* wp = (const float4*)(W + o * KDIM + kb);
            float4 w0 = wp[0];
            float4 w1 = wp[1];
            union { short8 v; unsigned int u[4]; } pk;
            pk.u[0] = pack_bf16(w0.x, w0.y);
            pk.u[1] = pack_bf16(w0.z, w0.w);
            pk.u[2] = pack_bf16(w1.x, w1.y);
            pk.u[3] = pack_bf16(w1.z, w1.w);
            bfrag[s] = pk.v;
        }
    }
    const float biasv = bias[w * 16 + ncol];
    const int off4  = tid & 31;
    const int sbase = tid >> 5;

    for (int ch = blockIdx.x; ch < nchunks; ch += gridDim.x) {
        const int vb = ch * VPC;
        __syncthreads();
#pragma unroll
        for (int i = 0; i < 14; ++i) {
            const int s  = sbase + 8 * i;
            const int lv = s / 7;
            const int k  = s - lv * 7;
            const int n  = vb + lv;
            int vi = 0;
            if (n < NV) vi = neigh[n * KN + k];
            const float4 g = ((const float4*)x)[vi * 32 + off4];
            const int base = k * 64 + 2 * off4;
            ((unsigned int*)A_lds)[((lv * 2)     * ASTRIDE + base) >> 1] = pack_bf16(g.x, g.z);
            ((unsigned int*)A_lds)[((lv * 2 + 1) * ASTRIDE + base) >> 1] = pack_bf16(g.y, g.w);
        }
        __syncthreads();
        f32x4 acc0 = {0.f, 0.f, 0.f, 0.f};
        f32x4 acc1 = {0.f, 0.f, 0.f, 0.f};
#pragma unroll
        for (int s = 0; s < KSTEPS; ++s) {
            const int kb = s * 32 + kgrp * 8;
            const short8 a0 = *(const short8*)&A_lds[ncol * ASTRIDE + kb];
            const short8 a1 = *(const short8*)&A_lds[(16 + ncol) * ASTRIDE + kb];
            acc0 = __builtin_amdgcn_mfma_f32_16x16x32_bf16(a0, bfrag[s], acc0, 0, 0, 0);
            acc1 = __builtin_amdgcn_mfma_f32_16x16x32_bf16(a1, bfrag[s], acc1, 0, 0, 0);
        }
        const int o = w * 16 + ncol;
#pragma unroll
        for (int j = 0; j < 4; ++j) {
            const int r = kgrp * 4 + j;
            {
                const int lv = r >> 1, bb = r & 1, n = vb + lv;
                if (n < NV) out[n * 128 + o * 2 + bb] = acc0[j] + biasv;
            }
            {
                const int m = 16 + r;
                const int lv = m >> 1, bb = m & 1, n = vb + lv;
                if (n < NV) out[n * 128 + o * 2 + bb] = acc1[j] + biasv;
            }
        }
    }
}

extern "C" void kernel_launch(void* const* d_in, const int* in_sizes, int n_in,
                              void* d_out, int out_size, void* d_ws, size_t ws_size,
                              hipStream_t stream) {
    const float* x     = (const float*)d_in[0];
    const int*   neigh = (const int*)d_in[1];   // int64 in ref -> int32 from harness
    const float* W     = (const float*)d_in[2];
    const float* bias  = (const float*)d_in[3];
    float*       out   = (float*)d_out;

    const int nchunks = (NV + VPC - 1) / VPC;   // 10241
    const size_t need = (size_t)2 * NV * 64 * sizeof(unsigned short);  // 41.9 MB

    if (ws_size >= need) {
        unsigned short* xt = (unsigned short*)d_ws;
        const int nf4 = NV * 32;
        xcast<<<dim3((nf4 + 255) / 256), dim3(256), 0, stream>>>(x, (unsigned int*)xt, nf4);
        onering_mfma_bf16<<<dim3(2560), dim3(256), 0, stream>>>(xt, neigh, W, bias, out, nchunks);
    } else {
        onering_mfma_f32<<<dim3(2560), dim3(256), 0, stream>>>(x, neigh, W, bias, out, nchunks);
    }
}